// Round 7
// baseline (81.265 us; speedup 1.0000x reference)
//
#include <hip/hip_runtime.h>

#define FD 128  // feature dim

typedef __attribute__((ext_vector_type(8))) short short8;   // 8 bf16
typedef __attribute__((ext_vector_type(4))) float f32x4;    // MFMA acc

__device__ __forceinline__ unsigned short f2bf(float f) {
    unsigned u = __float_as_uint(f);
    u += 0x7fff + ((u >> 16) & 1);   // round-to-nearest-even
    return (unsigned short)(u >> 16);
}

// ---------------------------------------------------------------------------
// Kernel 0: Wt[n][k] = bf16(W[k][n])  (128x128), short8 outputs.
// ---------------------------------------------------------------------------
__global__ void wt_kernel(const float* __restrict__ W, unsigned short* __restrict__ Wt) {
    const int tid = blockIdx.x * 256 + (int)threadIdx.x;   // 0..2047
    const int n  = tid & 127;
    const int k0 = (tid >> 7) * 8;
    short8 w;
    #pragma unroll
    for (int j = 0; j < 8; ++j) w[j] = (short)f2bf(W[(k0 + j) * FD + n]);
    *(short8*)(Wt + (size_t)n * FD + k0) = w;
}

// ---------------------------------------------------------------------------
// Kernel 1: u = bf16(z @ W) via MFMA 16x16x32; fused z->bf16 writeback.
// Wt staged in LDS (32 KB, XOR-swizzled). Epilogue repacks u through LDS
// so global u-stores are coalesced 16B. (Unchanged — verified rounds 4-6.)
// ---------------------------------------------------------------------------
__global__ __launch_bounds__(256)
void u_mfma2(const float* __restrict__ z, const unsigned short* __restrict__ Wt,
             unsigned short* __restrict__ u, unsigned short* __restrict__ zb,
             int nrows) {
    __shared__ unsigned short Wl[FD * FD];  // 32 KB
    char* ldsb = (char*)Wl;
    const int tid  = (int)threadIdx.x;
    const int lane = tid & 63;
    const int wave = tid >> 6;
    const int l16  = lane & 15;
    const int kq   = lane >> 4;

    #pragma unroll
    for (int i = 0; i < 8; ++i) {
        const int c = i * 256 + tid;
        const int n = c >> 4;
        const int o = (c & 15) * 16;
        short8 v = *(const short8*)(Wt + (size_t)n * FD + (c & 15) * 8);
        *(short8*)(ldsb + n * 256 + (o ^ ((n & 7) << 4))) = v;
    }
    __syncthreads();

    const long rowbase = (long)blockIdx.x * 128 + wave * 32;

    f32x4 acc[2][8];
    #pragma unroll
    for (int mt = 0; mt < 2; ++mt)
        #pragma unroll
        for (int nt = 0; nt < 8; ++nt)
            acc[mt][nt] = (f32x4){0.f, 0.f, 0.f, 0.f};

    #pragma unroll
    for (int ks = 0; ks < 4; ++ks) {
        const int k0 = ks * 32 + kq * 8;

        short8 a[2];
        #pragma unroll
        for (int mt = 0; mt < 2; ++mt) {
            const long r  = rowbase + mt * 16 + l16;
            const long rc = (r < nrows) ? r : (long)(nrows - 1);
            const float4* zp = (const float4*)(z + rc * FD + k0);
            const float4 f0 = zp[0];
            const float4 f1 = zp[1];
            short8 av;
            av[0] = (short)f2bf(f0.x); av[1] = (short)f2bf(f0.y);
            av[2] = (short)f2bf(f0.z); av[3] = (short)f2bf(f0.w);
            av[4] = (short)f2bf(f1.x); av[5] = (short)f2bf(f1.y);
            av[6] = (short)f2bf(f1.z); av[7] = (short)f2bf(f1.w);
            a[mt] = av;
            if (r < nrows)
                *(short8*)(zb + r * FD + k0) = av;
        }

        short8 b[8];
        #pragma unroll
        for (int nt = 0; nt < 8; ++nt) {
            const int row = nt * 16 + l16;
            b[nt] = *(const short8*)(ldsb + row * 256 + ((ks * 64 + kq * 16) ^ ((row & 7) << 4)));
        }

        #pragma unroll
        for (int mt = 0; mt < 2; ++mt)
            #pragma unroll
            for (int nt = 0; nt < 8; ++nt)
                acc[mt][nt] = __builtin_amdgcn_mfma_f32_16x16x32_bf16(
                    a[mt], b[nt], acc[mt][nt], 0, 0, 0);
    }

    __syncthreads();

    char* wb = ldsb + wave * 8192;
    #pragma unroll
    for (int mt = 0; mt < 2; ++mt)
        #pragma unroll
        for (int nt = 0; nt < 8; ++nt) {
            const f32x4 v = acc[mt][nt];
            #pragma unroll
            for (int r = 0; r < 4; ++r) {
                const int row = mt * 16 + kq * 4 + r;
                const int cb2 = (nt * 16 + l16) * 2;
                *(unsigned short*)(wb + row * 256 + (cb2 ^ ((row & 7) << 4))) = f2bf(v[r]);
            }
        }
    __syncthreads();
    #pragma unroll
    for (int i = 0; i < 8; ++i) {
        const int off = i * 1024 + lane * 16;
        const int row = off >> 8;
        const int inr = off & 255;
        short8 v = *(const short8*)(wb + (row << 8) + (inr ^ ((row & 7) << 4)));
        const long grow = rowbase + row;
        if (grow < nrows)
            *(short8*)(u + grow * FD + (inr >> 1)) = v;
    }
}

// ---------------------------------------------------------------------------
// Kernel 2: MFMA edge kernel, MLP-unrolled: one wave handles 32 edges per
// iteration (2 groups of 16). ALL 16 row-quarter loads (256 B/lane) are
// issued into registers BEFORE the MFMA chains, so the gathers overlap
// instead of serializing behind the dependent accumulator.
//   A[e][k]=u[src_e][k], B[k][e']=zb[dst_e'][k]; 4x mfma 16x16x32 per group;
//   diagonal D[e][e] = dot. D: lane l reg r -> row (l>>4)*4+r, col l&15;
//   diagonal at lanes with (l16>>2)==kq, reg r=l16&3.
// ---------------------------------------------------------------------------
__global__ __launch_bounds__(256)
void edge_mfma2(const unsigned short* __restrict__ u,
                const unsigned short* __restrict__ zb,
                const int* __restrict__ src, const int* __restrict__ dst,
                const float* __restrict__ bias, float* __restrict__ out, int E) {
    const int tid  = (int)threadIdx.x;
    const int lane = tid & 63;
    const int l16  = lane & 15;
    const int kq   = lane >> 4;
    const long wid = (long)blockIdx.x * 4 + (tid >> 6);
    const long nw  = (long)gridDim.x * 4;
    const float bv = bias[0];
    const bool isdiag = (l16 >> 2) == kq;
    const int  r = l16 & 3;

    for (long g = wid * 32; g < E; g += nw * 32) {
        const long ei0 = g + l16;
        const long ei1 = g + 16 + l16;
        const long ec0 = (ei0 < E) ? ei0 : (long)(E - 1);
        const long ec1 = (ei1 < E) ? ei1 : (long)(E - 1);
        const int s0 = src[ec0], t0 = dst[ec0];
        const int s1 = src[ec1], t1 = dst[ec1];
        const short8* up0 = (const short8*)(u  + (size_t)s0 * FD);
        const short8* zp0 = (const short8*)(zb + (size_t)t0 * FD);
        const short8* up1 = (const short8*)(u  + (size_t)s1 * FD);
        const short8* zp1 = (const short8*)(zb + (size_t)t1 * FD);

        short8 a0[4], b0[4], a1[4], b1[4];
        #pragma unroll
        for (int ks = 0; ks < 4; ++ks) {
            a0[ks] = up0[ks * 4 + kq];
            b0[ks] = zp0[ks * 4 + kq];
            a1[ks] = up1[ks * 4 + kq];
            b1[ks] = zp1[ks * 4 + kq];
        }

        f32x4 acc0 = (f32x4){0.f, 0.f, 0.f, 0.f};
        f32x4 acc1 = (f32x4){0.f, 0.f, 0.f, 0.f};
        #pragma unroll
        for (int ks = 0; ks < 4; ++ks) {
            acc0 = __builtin_amdgcn_mfma_f32_16x16x32_bf16(a0[ks], b0[ks], acc0, 0, 0, 0);
            acc1 = __builtin_amdgcn_mfma_f32_16x16x32_bf16(a1[ks], b1[ks], acc1, 0, 0, 0);
        }

        if (isdiag) {
            if (ei0 < E) {
                const float v = (r == 0) ? acc0[0] : (r == 1) ? acc0[1]
                              : (r == 2) ? acc0[2] : acc0[3];
                out[ei0] = v + bv;
            }
            if (ei1 < E) {
                const float v = (r == 0) ? acc1[0] : (r == 1) ? acc1[1]
                              : (r == 2) ? acc1[2] : acc1[3];
                out[ei1] = v + bv;
            }
        }
    }
}

// ---------------------------------------------------------------------------
// Fallback (workspace too small): fused per-edge bilinear, fp32.
// ---------------------------------------------------------------------------
__global__ __launch_bounds__(128)
void bilinear_fused_fallback(const float* __restrict__ z, const float* __restrict__ Wg,
                             const int* __restrict__ src, const int* __restrict__ dst,
                             const float* __restrict__ bias, float* __restrict__ out,
                             int E) {
    __shared__ float Wl[FD * FD];
    __shared__ float zs[FD];
    __shared__ float red[2];
    for (int i = threadIdx.x; i < FD * FD; i += 128) Wl[i] = Wg[i];
    __syncthreads();
    const int j = (int)threadIdx.x;
    for (int e = blockIdx.x; e < E; e += gridDim.x) {
        const int s = src[e];
        const int t = dst[e];
        zs[j] = z[(size_t)s * FD + j];
        __syncthreads();
        float acc = 0.f;
        #pragma unroll 8
        for (int d = 0; d < FD; ++d) acc += zs[d] * Wl[d * FD + j];
        float p = acc * z[(size_t)t * FD + j];
        #pragma unroll
        for (int off = 32; off >= 1; off >>= 1)
            p += __shfl_xor(p, off, 64);
        if ((j & 63) == 0) red[j >> 6] = p;
        __syncthreads();
        if (j == 0) out[e] = red[0] + red[1] + bias[0];
        __syncthreads();
    }
}

extern "C" void kernel_launch(void* const* d_in, const int* in_sizes, int n_in,
                              void* d_out, int out_size, void* d_ws, size_t ws_size,
                              hipStream_t stream) {
    const float* z    = (const float*)d_in[0];
    const int*   ei   = (const int*)d_in[1];
    const float* W    = (const float*)d_in[2];
    const float* bias = (const float*)d_in[3];
    float* out = (float*)d_out;

    const int nrows = in_sizes[0] / FD;
    const int E     = in_sizes[1] / 2;
    const int* src = ei;
    const int* dst = ei + E;

    const size_t szu = (size_t)nrows * FD * sizeof(unsigned short);  // 25.6 MB
    const size_t need = 2 * szu;   // u + zb

    if (ws_size >= need) {
        char* wsp = (char*)d_ws;
        unsigned short* u  = (unsigned short*)wsp;
        unsigned short* zb = (unsigned short*)(wsp + szu);
        unsigned short* Wt = (unsigned short*)d_out;   // 32 KB staging; edge pass
                                                       // later overwrites all of d_out

        wt_kernel<<<8, 256, 0, stream>>>(W, Wt);
        const int nb1 = (nrows + 127) / 128;
        u_mfma2<<<nb1, 256, 0, stream>>>(z, Wt, u, zb, nrows);
        edge_mfma2<<<2048, 256, 0, stream>>>(u, zb, src, dst, bias, out, E);
    } else {
        bilinear_fused_fallback<<<2048, 128, 0, stream>>>(z, W, src, dst, bias, out, E);
    }
}

// Round 8
// 73.048 us; speedup vs baseline: 1.1125x; 1.1125x over previous
//
#include <hip/hip_runtime.h>

#define FD 128  // feature dim

typedef __attribute__((ext_vector_type(8))) short short8;   // 8 bf16
typedef __attribute__((ext_vector_type(4))) float f32x4;    // MFMA acc
typedef __attribute__((ext_vector_type(4))) unsigned int uint4e;

__device__ __forceinline__ unsigned short f2bf(float f) {
    unsigned u = __float_as_uint(f);
    u += 0x7fff + ((u >> 16) & 1);   // round-to-nearest-even
    return (unsigned short)(u >> 16);
}
__device__ __forceinline__ float bfprod(unsigned a, unsigned b) {
    float a0 = __uint_as_float(a << 16);
    float a1 = __uint_as_float(a & 0xffff0000u);
    float b0 = __uint_as_float(b << 16);
    float b1 = __uint_as_float(b & 0xffff0000u);
    return __builtin_fmaf(a0, b0, a1 * b1);
}

// ---------------------------------------------------------------------------
// Kernel 0: Wt[n][k] = bf16(W[k][n])  (128x128), short8 outputs.
// ---------------------------------------------------------------------------
__global__ void wt_kernel(const float* __restrict__ W, unsigned short* __restrict__ Wt) {
    const int tid = blockIdx.x * 256 + (int)threadIdx.x;   // 0..2047
    const int n  = tid & 127;
    const int k0 = (tid >> 7) * 8;
    short8 w;
    #pragma unroll
    for (int j = 0; j < 8; ++j) w[j] = (short)f2bf(W[(k0 + j) * FD + n]);
    *(short8*)(Wt + (size_t)n * FD + k0) = w;
}

// ---------------------------------------------------------------------------
// Kernel 1 (v3): u = bf16(z @ W) via MFMA 16x16x32; fused z->bf16 writeback.
// Occupancy-focused restructure vs v2: ONE 16-row m-tile per wave (acc = 32
// VGPR instead of 64; ~105 total), 64 rows per 256-thread block. Wt in LDS
// (32 KB, XOR-swizzled); epilogue repacks u through the same LDS (after
// barrier) so global u-stores are coalesced 16 B.
// ---------------------------------------------------------------------------
__global__ __launch_bounds__(256)
void u_mfma3(const float* __restrict__ z, const unsigned short* __restrict__ Wt,
             unsigned short* __restrict__ u, unsigned short* __restrict__ zb,
             int nrows) {
    __shared__ unsigned short Wl[FD * FD];  // 32 KB
    char* ldsb = (char*)Wl;
    const int tid  = (int)threadIdx.x;
    const int lane = tid & 63;
    const int wave = tid >> 6;
    const int l16  = lane & 15;
    const int kq   = lane >> 4;

    // stage Wt -> LDS, swizzled: byte = n*256 + (o ^ ((n&7)<<4))
    #pragma unroll
    for (int i = 0; i < 8; ++i) {
        const int c = i * 256 + tid;
        const int n = c >> 4;
        const int o = (c & 15) * 16;
        short8 v = *(const short8*)(Wt + (size_t)n * FD + (c & 15) * 8);
        *(short8*)(ldsb + n * 256 + (o ^ ((n & 7) << 4))) = v;
    }
    __syncthreads();

    const long rowbase = (long)blockIdx.x * 64 + wave * 16;
    const long r  = rowbase + l16;
    const long rc = (r < nrows) ? r : (long)(nrows - 1);
    const bool rok = (r < nrows);

    f32x4 acc[8];
    #pragma unroll
    for (int nt = 0; nt < 8; ++nt)
        acc[nt] = (f32x4){0.f, 0.f, 0.f, 0.f};

    #pragma unroll
    for (int ks = 0; ks < 4; ++ks) {
        const int k0 = ks * 32 + kq * 8;

        const float4* zp = (const float4*)(z + rc * FD + k0);
        const float4 f0 = zp[0];
        const float4 f1 = zp[1];
        short8 av;
        av[0] = (short)f2bf(f0.x); av[1] = (short)f2bf(f0.y);
        av[2] = (short)f2bf(f0.z); av[3] = (short)f2bf(f0.w);
        av[4] = (short)f2bf(f1.x); av[5] = (short)f2bf(f1.y);
        av[6] = (short)f2bf(f1.z); av[7] = (short)f2bf(f1.w);
        if (rok)
            *(short8*)(zb + r * FD + k0) = av;

        #pragma unroll
        for (int nt = 0; nt < 8; ++nt) {
            const int row = nt * 16 + l16;
            const short8 b = *(const short8*)(
                ldsb + row * 256 + ((ks * 64 + kq * 16) ^ ((row & 7) << 4)));
            acc[nt] = __builtin_amdgcn_mfma_f32_16x16x32_bf16(av, b, acc[nt], 0, 0, 0);
        }
    }

    __syncthreads();   // all waves done reading Wt; reuse LDS for epilogue

    // wave repacks its 16x128 bf16 tile (4 KB) in its quarter of the W region
    char* wb = ldsb + wave * 4096;
    #pragma unroll
    for (int nt = 0; nt < 8; ++nt) {
        const f32x4 v = acc[nt];
        #pragma unroll
        for (int rr = 0; rr < 4; ++rr) {
            const int row = kq * 4 + rr;            // 0..15
            const int cb2 = (nt * 16 + l16) * 2;    // byte col
            *(unsigned short*)(wb + row * 256 + (cb2 ^ ((row & 7) << 4))) = f2bf(v[rr]);
        }
    }
    __syncthreads();
    #pragma unroll
    for (int i = 0; i < 4; ++i) {
        const int off = i * 1024 + lane * 16;   // 0..4095, 16B chunks
        const int row = off >> 8;               // 0..15
        const int inr = off & 255;
        short8 v = *(const short8*)(wb + (row << 8) + (inr ^ ((row & 7) << 4)));
        const long grow = rowbase + row;
        if (grow < nrows)
            *(short8*)(u + grow * FD + (inr >> 1)) = v;
    }
}

// ---------------------------------------------------------------------------
// Kernel 2: out[e] = dot(u_bf16[src], z_bf16[dst]) + b.
// Round-2 shuffle-dot variant — fastest measured edge kernel (45.4 us steady;
// MFMA-diag 48.5, MFMA-diag x2 51.5 — the phase is gather-BW bound at ~7 TB/s
// delivered / ~3.3 TB/s L2-miss path, so lowest-overhead variant wins).
// 16 lanes per edge, 16 B/lane; 4 edges/wave.
// ---------------------------------------------------------------------------
__global__ __launch_bounds__(256)
void edge_kernel_bf16(const unsigned short* __restrict__ u,
                      const unsigned short* __restrict__ zb,
                      const int* __restrict__ src, const int* __restrict__ dst,
                      const float* __restrict__ bias, float* __restrict__ out,
                      int E) {
    const int gw   = (blockIdx.x * 256 + (int)threadIdx.x) >> 6;
    const int lane = (int)threadIdx.x & 63;
    const int sub  = lane >> 4;
    const int l16  = lane & 15;
    const int e    = gw * 4 + sub;
    if (e >= E) return;
    const int s = src[e];
    const int t = dst[e];
    const uint4e ua = *((const uint4e*)(u  + (size_t)s * FD) + l16);
    const uint4e za = *((const uint4e*)(zb + (size_t)t * FD) + l16);
    float sum = bfprod(ua[0], za[0]) + bfprod(ua[1], za[1])
              + bfprod(ua[2], za[2]) + bfprod(ua[3], za[3]);
    #pragma unroll
    for (int off = 8; off >= 1; off >>= 1)
        sum += __shfl_xor(sum, off, 64);
    if (l16 == 0) out[e] = sum + bias[0];
}

// ---------------------------------------------------------------------------
// Fallback (workspace too small): fused per-edge bilinear, fp32.
// ---------------------------------------------------------------------------
__global__ __launch_bounds__(128)
void bilinear_fused_fallback(const float* __restrict__ z, const float* __restrict__ Wg,
                             const int* __restrict__ src, const int* __restrict__ dst,
                             const float* __restrict__ bias, float* __restrict__ out,
                             int E) {
    __shared__ float Wl[FD * FD];
    __shared__ float zs[FD];
    __shared__ float red[2];
    for (int i = threadIdx.x; i < FD * FD; i += 128) Wl[i] = Wg[i];
    __syncthreads();
    const int j = (int)threadIdx.x;
    for (int e = blockIdx.x; e < E; e += gridDim.x) {
        const int s = src[e];
        const int t = dst[e];
        zs[j] = z[(size_t)s * FD + j];
        __syncthreads();
        float acc = 0.f;
        #pragma unroll 8
        for (int d = 0; d < FD; ++d) acc += zs[d] * Wl[d * FD + j];
        float p = acc * z[(size_t)t * FD + j];
        #pragma unroll
        for (int off = 32; off >= 1; off >>= 1)
            p += __shfl_xor(p, off, 64);
        if ((j & 63) == 0) red[j >> 6] = p;
        __syncthreads();
        if (j == 0) out[e] = red[0] + red[1] + bias[0];
        __syncthreads();
    }
}

extern "C" void kernel_launch(void* const* d_in, const int* in_sizes, int n_in,
                              void* d_out, int out_size, void* d_ws, size_t ws_size,
                              hipStream_t stream) {
    const float* z    = (const float*)d_in[0];
    const int*   ei   = (const int*)d_in[1];
    const float* W    = (const float*)d_in[2];
    const float* bias = (const float*)d_in[3];
    float* out = (float*)d_out;

    const int nrows = in_sizes[0] / FD;
    const int E     = in_sizes[1] / 2;
    const int* src = ei;
    const int* dst = ei + E;

    const size_t szu = (size_t)nrows * FD * sizeof(unsigned short);  // 25.6 MB
    const size_t need = 2 * szu;   // u + zb

    if (ws_size >= need) {
        char* wsp = (char*)d_ws;
        unsigned short* u  = (unsigned short*)wsp;
        unsigned short* zb = (unsigned short*)(wsp + szu);
        unsigned short* Wt = (unsigned short*)d_out;   // 32 KB staging; edge pass
                                                       // later overwrites all of d_out

        wt_kernel<<<8, 256, 0, stream>>>(W, Wt);
        const int nb1 = (nrows + 63) / 64;
        u_mfma3<<<nb1, 256, 0, stream>>>(z, Wt, u, zb, nrows);
        const int nb2 = (E + 15) / 16;
        edge_kernel_bf16<<<nb2, 256, 0, stream>>>(u, zb, src, dst, bias, out, E);
    } else {
        bilinear_fused_fallback<<<2048, 128, 0, stream>>>(z, W, src, dst, bias, out, E);
    }
}